// Round 4
// baseline (1244.135 us; speedup 1.0000x reference)
//
#include <hip/hip_runtime.h>

#define N_NODES 50000
#define N_EDGES 800000
#define DIM 64
#define N_LAYERS 3
#define N_GRAPHS 256
#define BN_EPS 1e-5f
#define D3 (DIM * N_LAYERS)
#define N_PART 64
#define NBKT 782          // ceil(50000/64) destination buckets = MFMA tiles
#define NSUB 8            // sub-buckets (approx XCD) for write locality
#define NCTR (NBKT * NSUB)
#define TS 68             // LDS tile stride (floats): breaks bank conflicts, 16B aligned

typedef __attribute__((ext_vector_type(8))) short short8;
typedef __attribute__((ext_vector_type(4))) float floatx4;

// ---------------------------------------------------------- bf16 split utils
__device__ inline unsigned short bf16_rn(float f) {
    unsigned u = __float_as_uint(f);
    u += 0x7FFF + ((u >> 16) & 1);
    return (unsigned short)(u >> 16);
}
__device__ inline float bf16_f(unsigned short b) {
    return __uint_as_float(((unsigned)b) << 16);
}
__device__ inline void split8(float4 a, float4 b, short8* hi, short8* lo) {
    float v[8] = {a.x, a.y, a.z, a.w, b.x, b.y, b.z, b.w};
#pragma unroll
    for (int i = 0; i < 8; i++) {
        unsigned short h = bf16_rn(v[i]);
        (*hi)[i] = (short)h;
        (*lo)[i] = (short)bf16_rn(v[i] - bf16_f(h));
    }
}

// ---------------------------------------------- pass 1: per-(bucket,sub) hist
__global__ __launch_bounds__(256) void pass1_hist(const int* __restrict__ dst,
                                                  int* __restrict__ bcnt) {
    __shared__ int hcnt[NBKT];
    for (int i = threadIdx.x; i < NBKT; i += 256) hcnt[i] = 0;
    __syncthreads();
    int sub = blockIdx.x & (NSUB - 1);
    int base = blockIdx.x * 4096;
#pragma unroll
    for (int k = 0; k < 16; k++) {
        int e = base + k * 256 + threadIdx.x;
        if (e < N_EDGES) atomicAdd(&hcnt[dst[e] >> 6], 1);
    }
    __syncthreads();
    for (int i = threadIdx.x; i < NBKT; i += 256) {
        int c = hcnt[i];
        if (c) atomicAdd(&bcnt[i * NSUB + sub], c);
    }
}

// -------------------------------------- exclusive scan of 6256 counters (1 blk)
__global__ __launch_bounds__(1024) void scan_all(const int* __restrict__ bcnt,
                                                 int* __restrict__ boff) {
    __shared__ int tsum[1024];
    int t = threadIdx.x;
    const int C = (NCTR + 1023) / 1024;   // 7
    int base = t * C;
    int loc[7];
    int s = 0;
    for (int i = 0; i < C; i++) {
        int idx = base + i;
        int v = (idx < NCTR) ? bcnt[idx] : 0;
        loc[i] = s;
        s += v;
    }
    tsum[t] = s;
    __syncthreads();
    for (int off = 1; off < 1024; off <<= 1) {
        int v = (t >= off) ? tsum[t - off] : 0;
        __syncthreads();
        tsum[t] += v;
        __syncthreads();
    }
    int excl = (t > 0) ? tsum[t - 1] : 0;
    for (int i = 0; i < C; i++) {
        int idx = base + i;
        if (idx < NCTR) boff[idx] = excl + loc[i];
    }
    if (t == 0) boff[NCTR] = N_EDGES;
}

// ------------------------- pass 2: partition edges, pack src<<6 | (dst&63)
__global__ __launch_bounds__(256) void pass2_part(const int* __restrict__ src,
                                                  const int* __restrict__ dst,
                                                  const int* __restrict__ boff,
                                                  int* __restrict__ bfill,
                                                  unsigned* __restrict__ ebuf) {
    int sub = blockIdx.x & (NSUB - 1);
    int base = blockIdx.x * 4096;
#pragma unroll
    for (int k = 0; k < 16; k++) {
        int e = base + k * 256 + threadIdx.x;
        if (e < N_EDGES) {
            int d = dst[e];
            int b = d >> 6;
            int pos = boff[b * NSUB + sub] + atomicAdd(&bfill[b * NSUB + sub], 1);
            ebuf[pos] = ((unsigned)src[e] << 6) | (unsigned)(d & 63);
        }
    }
}

// --------------- pack W1/W2 into MFMA B-operand fragments, split bf16 hi/lo
__global__ __launch_bounds__(256) void prep_weights(const float* __restrict__ W1,
                                                    const float* __restrict__ W2,
                                                    unsigned short* __restrict__ wf) {
    int idx = blockIdx.x * 256 + threadIdx.x;
    if (idx >= N_LAYERS * 2 * 4096) return;
    int j    = idx & 7;
    int lane = (idx >> 3) & 63;
    int ks   = (idx >> 9) & 1;
    int nt   = (idx >> 10) & 3;
    int gemm = (idx >> 12) & 1;
    int layer = idx >> 13;
    int n = nt * 16 + (lane & 15);
    int k = ks * 32 + (lane >> 4) * 8 + j;
    const float* W = (gemm ? W2 : W1) + (size_t)layer * DIM * DIM;
    float w = W[k * DIM + n];
    unsigned short hi = bf16_rn(w);
    unsigned short lo = bf16_rn(w - bf16_f(hi));
    size_t base = ((size_t)layer * 2 + gemm) * 8192;
    int f = nt * 2 + ks;
    wf[base + f * 512 + lane * 8 + j]        = hi;
    wf[base + 4096 + f * 512 + lane * 8 + j] = lo;
}

// -------------------------------------------- per-graph node counts (sorted)
__global__ __launch_bounds__(256) void count_graphs(const int* __restrict__ batch,
                                                    int* __restrict__ cntg) {
    int grp = blockIdx.x * 256 + threadIdx.x;
    if (grp >= N_NODES / 8) return;
    int n0 = grp * 8, run = 0, cur = batch[n0];
#pragma unroll
    for (int r = 0; r < 8; r++) {
        int b = batch[n0 + r];
        if (b != cur) { atomicAdd(&cntg[cur], run); run = 0; cur = b; }
        run++;
    }
    atomicAdd(&cntg[cur], run);
}

// ================= fused layer: gather(+BN of prev) -> MFMA MLP -> stats/pool
// block = bucket = 64 consecutive dst nodes = one MFMA row tile
__global__ __launch_bounds__(256) void gin_layer(
    const float* __restrict__ h, const float* __restrict__ ss,   // ss==null -> identity
    const unsigned* __restrict__ ebuf, const int* __restrict__ boff,
    const unsigned short* __restrict__ wfL,
    const float* __restrict__ B1, const float* __restrict__ B2,
    float* __restrict__ z_out, int write_z,
    float* __restrict__ sums_part, float* __restrict__ praw,
    const int* __restrict__ batch) {
    __shared__ float tile[64 * TS];
    __shared__ float sH[4][16 * TS];
    __shared__ float sSum[2 * DIM];
    __shared__ int   sBatch[64];

    int tid = threadIdx.x, wave = tid >> 6, lane = tid & 63;
    float sc = ss ? ss[lane] : 1.f;
    float sh = ss ? ss[DIM + lane] : 0.f;
    if (tid < 2 * DIM) sSum[tid] = 0.f;
    int row0 = blockIdx.x * 64;
    if (tid < 64) sBatch[tid] = (row0 + tid < N_NODES) ? batch[row0 + tid] : -1;

    // ---- tile init: own rows + affine(prev BN)
#pragma unroll
    for (int r = 0; r < 16; r++) {
        int row = wave * 16 + r, grow = row0 + row;
        float v = 0.f;
        if (grow < N_NODES) v = fmaf(h[(size_t)grow * DIM + lane], sc, sh);
        tile[row * TS + lane] = v;
    }
    __syncthreads();

    // ---- edge gather into LDS (f32 LDS atomics)
    int estart = boff[blockIdx.x * NSUB];
    int eend   = boff[blockIdx.x * NSUB + NSUB];
    int total = eend - estart;
    int chunk = (total + 3) >> 2;
    int a0 = estart + wave * chunk;
    int a1 = a0 + chunk; if (a1 > eend) a1 = eend;
    int i = a0;
    for (; i + 4 <= a1; i += 4) {
        unsigned e0 = ebuf[i], e1 = ebuf[i + 1], e2 = ebuf[i + 2], e3 = ebuf[i + 3];
        float v0 = h[((size_t)(e0 >> 6)) * DIM + lane];
        float v1 = h[((size_t)(e1 >> 6)) * DIM + lane];
        float v2 = h[((size_t)(e2 >> 6)) * DIM + lane];
        float v3 = h[((size_t)(e3 >> 6)) * DIM + lane];
        atomicAdd(&tile[(e0 & 63) * TS + lane], fmaf(v0, sc, sh));
        atomicAdd(&tile[(e1 & 63) * TS + lane], fmaf(v1, sc, sh));
        atomicAdd(&tile[(e2 & 63) * TS + lane], fmaf(v2, sc, sh));
        atomicAdd(&tile[(e3 & 63) * TS + lane], fmaf(v3, sc, sh));
    }
    for (; i < a1; i++) {
        unsigned e = ebuf[i];
        float v = h[((size_t)(e >> 6)) * DIM + lane];
        atomicAdd(&tile[(e & 63) * TS + lane], fmaf(v, sc, sh));
    }
    __syncthreads();

    // ---- A fragments straight from LDS tile
    int m = lane & 15, quad = lane >> 4;
    const float* tw = &tile[(wave * 16 + m) * TS];
    float4 a0f = *(const float4*)&tw[quad * 8];
    float4 a1f = *(const float4*)&tw[quad * 8 + 4];
    float4 a2f = *(const float4*)&tw[32 + quad * 8];
    float4 a3f = *(const float4*)&tw[32 + quad * 8 + 4];
    short8 Ah0, Al0, Ah1, Al1;
    split8(a0f, a1f, &Ah0, &Al0);
    split8(a2f, a3f, &Ah1, &Al1);

    // ---- GEMM1 (split-bf16: AhBh + AhBl + AlBh)
    floatx4 acc[4];
#pragma unroll
    for (int nt = 0; nt < 4; nt++) acc[nt] = (floatx4){0.f, 0.f, 0.f, 0.f};
#pragma unroll
    for (int nt = 0; nt < 4; nt++) {
#pragma unroll
        for (int ks = 0; ks < 2; ks++) {
            const short8 Bh = *(const short8*)(wfL + (nt * 2 + ks) * 512 + lane * 8);
            const short8 Bl = *(const short8*)(wfL + 4096 + (nt * 2 + ks) * 512 + lane * 8);
            short8 Ahf = ks ? Ah1 : Ah0;
            short8 Alf = ks ? Al1 : Al0;
            acc[nt] = __builtin_amdgcn_mfma_f32_16x16x32_bf16(Ahf, Bh, acc[nt], 0, 0, 0);
            acc[nt] = __builtin_amdgcn_mfma_f32_16x16x32_bf16(Ahf, Bl, acc[nt], 0, 0, 0);
            acc[nt] = __builtin_amdgcn_mfma_f32_16x16x32_bf16(Alf, Bh, acc[nt], 0, 0, 0);
        }
    }

    // ---- bias+relu, park hidden in wave-private LDS, reload as A-fragments
    float* Hs = sH[wave];
#pragma unroll
    for (int nt = 0; nt < 4; nt++) {
        int col = nt * 16 + m;
        float b = B1[col];
#pragma unroll
        for (int r = 0; r < 4; r++) {
            int lr = quad * 4 + r;
            Hs[lr * TS + col] = fmaxf(acc[nt][r] + b, 0.f);
        }
    }
    float4 h0 = *(const float4*)&Hs[m * TS + quad * 8];
    float4 h1 = *(const float4*)&Hs[m * TS + quad * 8 + 4];
    float4 h2 = *(const float4*)&Hs[m * TS + 32 + quad * 8];
    float4 h3 = *(const float4*)&Hs[m * TS + 32 + quad * 8 + 4];
    short8 Hh0, Hl0, Hh1, Hl1;
    split8(h0, h1, &Hh0, &Hl0);
    split8(h2, h3, &Hh1, &Hl1);

    // ---- GEMM2
    floatx4 acc2[4];
#pragma unroll
    for (int nt = 0; nt < 4; nt++) acc2[nt] = (floatx4){0.f, 0.f, 0.f, 0.f};
    const unsigned short* wg2 = wfL + 8192;
#pragma unroll
    for (int nt = 0; nt < 4; nt++) {
#pragma unroll
        for (int ks = 0; ks < 2; ks++) {
            const short8 Bh = *(const short8*)(wg2 + (nt * 2 + ks) * 512 + lane * 8);
            const short8 Bl = *(const short8*)(wg2 + 4096 + (nt * 2 + ks) * 512 + lane * 8);
            short8 Ahf = ks ? Hh1 : Hh0;
            short8 Alf = ks ? Hl1 : Hl0;
            acc2[nt] = __builtin_amdgcn_mfma_f32_16x16x32_bf16(Ahf, Bh, acc2[nt], 0, 0, 0);
            acc2[nt] = __builtin_amdgcn_mfma_f32_16x16x32_bf16(Ahf, Bl, acc2[nt], 0, 0, 0);
            acc2[nt] = __builtin_amdgcn_mfma_f32_16x16x32_bf16(Alf, Bh, acc2[nt], 0, 0, 0);
        }
    }

    // ---- epilogue: z write + BN partials + per-graph raw pooling
    int gfirst = sBatch[wave * 16], glast = sBatch[wave * 16 + 15];
    bool uni = (gfirst == glast) && (gfirst >= 0);
#pragma unroll
    for (int nt = 0; nt < 4; nt++) {
        int col = nt * 16 + m;
        float b = B2[col];
        float vv[4];
        float s = 0.f, s2 = 0.f;
#pragma unroll
        for (int r = 0; r < 4; r++) {
            int gr = row0 + wave * 16 + quad * 4 + r;
            float v = fmaxf(acc2[nt][r] + b, 0.f);
            if (gr < N_NODES) {
                if (write_z) z_out[(size_t)gr * DIM + col] = v;
                s += v;
                s2 = fmaf(v, v, s2);
                vv[r] = v;
            } else {
                vv[r] = 0.f;
            }
        }
        float sf = s, s2f = s2;
        sf  += __shfl_xor(sf, 16);  sf  += __shfl_xor(sf, 32);
        s2f += __shfl_xor(s2f, 16); s2f += __shfl_xor(s2f, 32);
        if (quad == 0) {
            atomicAdd(&sSum[col], sf);
            atomicAdd(&sSum[DIM + col], s2f);
            if (uni) atomicAdd(&praw[(size_t)gfirst * DIM + col], sf);
        }
        if (!uni) {
            int cur = -1; float run = 0.f;
#pragma unroll
            for (int r = 0; r < 4; r++) {
                int g = sBatch[wave * 16 + quad * 4 + r];
                if (g != cur) {
                    if (cur >= 0 && run != 0.f)
                        atomicAdd(&praw[(size_t)cur * DIM + col], run);
                    run = 0.f; cur = g;
                }
                run += vv[r];
            }
            if (cur >= 0 && run != 0.f)
                atomicAdd(&praw[(size_t)cur * DIM + col], run);
        }
    }
    __syncthreads();
    if (tid < 2 * DIM)
        atomicAdd(&sums_part[(size_t)(blockIdx.x & (N_PART - 1)) * 2 * DIM + tid], sSum[tid]);
}

// --------------------------------------------- BN scale/shift from partials
__global__ void finalize_stats(const float* __restrict__ sp,
                               const float* __restrict__ gamma,
                               const float* __restrict__ beta,
                               float* __restrict__ ss) {
    int c = threadIdx.x;
    float s = 0.f, q = 0.f;
    for (int p = 0; p < N_PART; p++) {
        s += sp[p * 2 * DIM + c];
        q += sp[p * 2 * DIM + DIM + c];
    }
    const float inv_n = 1.0f / (float)N_NODES;
    float mu  = s * inv_n;
    float var = q * inv_n - mu * mu;
    float scale = gamma[c] / sqrtf(var + BN_EPS);
    ss[c]       = scale;
    ss[DIM + c] = beta[c] - mu * scale;
}

// ------------------- pooled[g][L*64+c] = sc*praw + cnt_g*sh (affine on pools)
__global__ __launch_bounds__(256) void assemble_pooled(const float* __restrict__ praw,
                                                       const float* __restrict__ ssAll,
                                                       const int* __restrict__ cntg,
                                                       float* __restrict__ pooled) {
    int idx = blockIdx.x * 256 + threadIdx.x;
    if (idx >= N_GRAPHS * D3) return;
    int g = idx / D3, j = idx - g * D3, L = j >> 6, c = j & 63;
    float sc = ssAll[L * 2 * DIM + c], sh = ssAll[L * 2 * DIM + DIM + c];
    pooled[idx] = fmaf(sc, praw[((size_t)L * N_GRAPHS + g) * DIM + c],
                       (float)cntg[g] * sh);
}

// ------------------------------------------------ final 2-layer MLP on pooled
__global__ __launch_bounds__(192) void final_mlp(const float* __restrict__ pooled,
    const float* __restrict__ PW1, const float* __restrict__ PB1,
    const float* __restrict__ PW2, const float* __restrict__ PB2,
    float* __restrict__ out) {
    __shared__ float row[D3];
    __shared__ float hid[D3];
    int g = blockIdx.x, j = threadIdx.x;
    row[j] = pooled[(size_t)g * D3 + j];
    __syncthreads();
    float acc = PB1[j];
    for (int k = 0; k < D3; k++) acc = fmaf(row[k], PW1[k * D3 + j], acc);
    hid[j] = fmaxf(acc, 0.f);
    __syncthreads();
    float acc2 = PB2[j];
    for (int k = 0; k < D3; k++) acc2 = fmaf(hid[k], PW2[k * D3 + j], acc2);
    out[(size_t)g * D3 + j] = acc2;
}

extern "C" void kernel_launch(void* const* d_in, const int* in_sizes, int n_in,
                              void* d_out, int out_size, void* d_ws, size_t ws_size,
                              hipStream_t stream) {
    const float* x     = (const float*)d_in[0];
    const int*   ei    = (const int*)d_in[1];
    const int*   batch = (const int*)d_in[2];
    const float* W1    = (const float*)d_in[3];
    const float* B1    = (const float*)d_in[4];
    const float* W2    = (const float*)d_in[5];
    const float* B2    = (const float*)d_in[6];
    const float* gamma = (const float*)d_in[7];
    const float* beta  = (const float*)d_in[8];
    const float* PW1   = (const float*)d_in[9];
    const float* PB1   = (const float*)d_in[10];
    const float* PW2   = (const float*)d_in[11];
    const float* PB2   = (const float*)d_in[12];
    float* out = (float*)d_out;

    // -------- workspace layout (floats; all regions 16B aligned)
    float*    bufA   = (float*)d_ws;                               // 3,200,000
    float*    bufB   = bufA + (size_t)N_NODES * DIM;               // 3,200,000
    unsigned* ebuf   = (unsigned*)(bufB + (size_t)N_NODES * DIM);  // 800,000
    int*      boff   = (int*)(ebuf + N_EDGES);                     // 6,260 (6257 pad 6260)
    unsigned short* wfrag = (unsigned short*)(boff + 6260);        // 49,152 u16
    float*    ssbuf  = (float*)(wfrag + 49152);                    // 384
    float*    pooled = ssbuf + N_LAYERS * 2 * DIM;                 // 49,152
    // ---- zeroed region starts here
    int*      bcnt   = (int*)(pooled + N_GRAPHS * D3);             // 6,256
    int*      bfill  = bcnt + NCTR;                                // 6,256
    int*      cntg   = bfill + NCTR;                               // 256
    float*    sums_part = (float*)(cntg + N_GRAPHS);               // 3*64*128
    float*    praw   = sums_part + N_LAYERS * N_PART * 2 * DIM;    // 3*256*64

    const int* src = ei;
    const int* dst = ei + N_EDGES;

    const size_t zero_bytes =
        (size_t)(2 * NCTR + N_GRAPHS) * sizeof(int) +
        (size_t)(N_LAYERS * N_PART * 2 * DIM + N_LAYERS * N_GRAPHS * DIM) * sizeof(float);
    hipMemsetAsync(bcnt, 0, zero_bytes, stream);

    // -------- edge partition + weight prep + graph counts
    const int PB = (N_EDGES + 4095) / 4096;       // 196
    pass1_hist<<<PB, 256, 0, stream>>>(dst, bcnt);
    scan_all<<<1, 1024, 0, stream>>>(bcnt, boff);
    pass2_part<<<PB, 256, 0, stream>>>(src, dst, boff, bfill, ebuf);
    prep_weights<<<(N_LAYERS * 2 * 4096 + 255) / 256, 256, 0, stream>>>(W1, W2, wfrag);
    count_graphs<<<(N_NODES / 8 + 255) / 256, 256, 0, stream>>>(batch, cntg);

    // -------- fused layers
    const float* P = x;
    float* Q = bufA;
    const float* ssPrev = nullptr;     // identity for layer 0
    for (int L = 0; L < N_LAYERS; ++L) {
        int write_z = (L < N_LAYERS - 1);
        gin_layer<<<NBKT, 256, 0, stream>>>(
            P, ssPrev, ebuf, boff,
            wfrag + (size_t)L * 2 * 8192,
            B1 + (size_t)L * DIM, B2 + (size_t)L * DIM,
            Q, write_z,
            sums_part + (size_t)L * N_PART * 2 * DIM,
            praw + (size_t)L * N_GRAPHS * DIM,
            batch);
        finalize_stats<<<1, DIM, 0, stream>>>(sums_part + (size_t)L * N_PART * 2 * DIM,
                                              gamma + (size_t)L * DIM,
                                              beta + (size_t)L * DIM,
                                              ssbuf + (size_t)L * 2 * DIM);
        ssPrev = ssbuf + (size_t)L * 2 * DIM;
        P = Q;
        Q = (Q == bufA) ? bufB : bufA;
    }

    assemble_pooled<<<(N_GRAPHS * D3 + 255) / 256, 256, 0, stream>>>(praw, ssbuf, cntg, pooled);
    final_mlp<<<N_GRAPHS, 192, 0, stream>>>(pooled, PW1, PB1, PW2, PB2, out);
}

// Round 5
// 1241.169 us; speedup vs baseline: 1.0024x; 1.0024x over previous
//
#include <hip/hip_runtime.h>

#define N_NODES 50000
#define N_EDGES 800000
#define DIM 64
#define N_LAYERS 3
#define N_GRAPHS 256
#define BN_EPS 1e-5f
#define D3 (DIM * N_LAYERS)
#define N_PART 64
#define NBKT 782          // ceil(50000/64) destination buckets = MFMA tiles
#define NSUB 8
#define NCTR (NBKT * NSUB)
#define TS 68             // LDS tile stride

typedef __attribute__((ext_vector_type(8))) short short8;
typedef __attribute__((ext_vector_type(4))) float floatx4;

// native LDS f32 add (HIP atomicAdd on LDS float expands to a CAS loop when
// f32 denormals are enabled — this forces the single-instruction ds_add_f32;
// LDS aperture is 4GB-aligned on gfx9 so low 32 bits of generic ptr = offset)
__device__ __forceinline__ void lds_fadd(float* p, float v) {
    unsigned off = (unsigned)(unsigned long long)p;
    asm volatile("ds_add_f32 %0, %1" : : "v"(off), "v"(v));
}

// ---------------------------------------------------------- bf16 split utils
__device__ inline unsigned short bf16_rn(float f) {
    unsigned u = __float_as_uint(f);
    u += 0x7FFF + ((u >> 16) & 1);
    return (unsigned short)(u >> 16);
}
__device__ inline float bf16_f(unsigned short b) {
    return __uint_as_float(((unsigned)b) << 16);
}
__device__ inline void split8(float4 a, float4 b, short8* hi, short8* lo) {
    float v[8] = {a.x, a.y, a.z, a.w, b.x, b.y, b.z, b.w};
#pragma unroll
    for (int i = 0; i < 8; i++) {
        unsigned short h = bf16_rn(v[i]);
        (*hi)[i] = (short)h;
        (*lo)[i] = (short)bf16_rn(v[i] - bf16_f(h));
    }
}
__device__ inline float4 affine4(float4 t, float4 sc, float degf, float4 sh) {
    float4 r;
    r.x = fmaf(t.x, sc.x, degf * sh.x);
    r.y = fmaf(t.y, sc.y, degf * sh.y);
    r.z = fmaf(t.z, sc.z, degf * sh.z);
    r.w = fmaf(t.w, sc.w, degf * sh.w);
    return r;
}

// ---------------------------------------------- pass 1: per-(bucket,sub) hist
__global__ __launch_bounds__(256) void pass1_hist(const int* __restrict__ dst,
                                                  int* __restrict__ bcnt) {
    __shared__ int hcnt[NBKT];
    for (int i = threadIdx.x; i < NBKT; i += 256) hcnt[i] = 0;
    __syncthreads();
    int sub = blockIdx.x & (NSUB - 1);
    int base = blockIdx.x * 4096;
#pragma unroll
    for (int k = 0; k < 16; k++) {
        int e = base + k * 256 + threadIdx.x;
        if (e < N_EDGES) atomicAdd(&hcnt[dst[e] >> 6], 1);
    }
    __syncthreads();
    for (int i = threadIdx.x; i < NBKT; i += 256) {
        int c = hcnt[i];
        if (c) atomicAdd(&bcnt[i * NSUB + sub], c);
    }
}

// -------------------------------------- exclusive scan of 6256 counters
__global__ __launch_bounds__(1024) void scan_all(const int* __restrict__ bcnt,
                                                 int* __restrict__ boff) {
    __shared__ int tsum[1024];
    int t = threadIdx.x;
    const int C = (NCTR + 1023) / 1024;
    int base = t * C;
    int loc[7];
    int s = 0;
    for (int i = 0; i < C; i++) {
        int idx = base + i;
        int v = (idx < NCTR) ? bcnt[idx] : 0;
        loc[i] = s;
        s += v;
    }
    tsum[t] = s;
    __syncthreads();
    for (int off = 1; off < 1024; off <<= 1) {
        int v = (t >= off) ? tsum[t - off] : 0;
        __syncthreads();
        tsum[t] += v;
        __syncthreads();
    }
    int excl = (t > 0) ? tsum[t - 1] : 0;
    for (int i = 0; i < C; i++) {
        int idx = base + i;
        if (idx < NCTR) boff[idx] = excl + loc[i];
    }
    if (t == 0) boff[NCTR] = N_EDGES;
}

// ------------------------- pass 2: partition edges, pack src<<6 | (dst&63)
__global__ __launch_bounds__(256) void pass2_part(const int* __restrict__ src,
                                                  const int* __restrict__ dst,
                                                  const int* __restrict__ boff,
                                                  int* __restrict__ bfill,
                                                  unsigned* __restrict__ ebuf) {
    int sub = blockIdx.x & (NSUB - 1);
    int base = blockIdx.x * 4096;
#pragma unroll
    for (int k = 0; k < 16; k++) {
        int e = base + k * 256 + threadIdx.x;
        if (e < N_EDGES) {
            int d = dst[e];
            int b = d >> 6;
            int pos = boff[b * NSUB + sub] + atomicAdd(&bfill[b * NSUB + sub], 1);
            ebuf[pos] = ((unsigned)src[e] << 6) | (unsigned)(d & 63);
        }
    }
}

// --------------- pack W1/W2 into MFMA B-operand fragments, split bf16 hi/lo
__global__ __launch_bounds__(256) void prep_weights(const float* __restrict__ W1,
                                                    const float* __restrict__ W2,
                                                    unsigned short* __restrict__ wf) {
    int idx = blockIdx.x * 256 + threadIdx.x;
    if (idx >= N_LAYERS * 2 * 4096) return;
    int j    = idx & 7;
    int lane = (idx >> 3) & 63;
    int ks   = (idx >> 9) & 1;
    int nt   = (idx >> 10) & 3;
    int gemm = (idx >> 12) & 1;
    int layer = idx >> 13;
    int n = nt * 16 + (lane & 15);
    int k = ks * 32 + (lane >> 4) * 8 + j;
    const float* W = (gemm ? W2 : W1) + (size_t)layer * DIM * DIM;
    float w = W[k * DIM + n];
    unsigned short hi = bf16_rn(w);
    unsigned short lo = bf16_rn(w - bf16_f(hi));
    size_t base = ((size_t)layer * 2 + gemm) * 8192;
    int f = nt * 2 + ks;
    wf[base + f * 512 + lane * 8 + j]        = hi;
    wf[base + 4096 + f * 512 + lane * 8 + j] = lo;
}

// -------------------------------------------- per-graph node counts (sorted)
__global__ __launch_bounds__(256) void count_graphs(const int* __restrict__ batch,
                                                    int* __restrict__ cntg) {
    int grp = blockIdx.x * 256 + threadIdx.x;
    if (grp >= N_NODES / 8) return;
    int n0 = grp * 8, run = 0, cur = batch[n0];
#pragma unroll
    for (int r = 0; r < 8; r++) {
        int b = batch[n0 + r];
        if (b != cur) { atomicAdd(&cntg[cur], run); run = 0; cur = b; }
        run++;
    }
    atomicAdd(&cntg[cur], run);
}

// ================= fused layer: raw gather -> affine -> MFMA MLP -> stats/pool
__global__ __launch_bounds__(256) void gin_layer(
    const float* __restrict__ h, const float* __restrict__ ss,   // ss==null -> identity
    const unsigned* __restrict__ ebuf, const int* __restrict__ boff,
    const unsigned short* __restrict__ wfL,
    const float* __restrict__ B1, const float* __restrict__ B2,
    float* __restrict__ z_out, int write_z,
    float* __restrict__ sums_part, float* __restrict__ praw,
    const int* __restrict__ batch) {
    __shared__ float tile[64 * TS];
    __shared__ float sH[4][16 * TS];
    __shared__ float sSum[2 * DIM];
    __shared__ int   sBatch[64];
    __shared__ int   sDeg[64];

    int tid = threadIdx.x, wave = tid >> 6, lane = tid & 63;
    if (tid < 2 * DIM) sSum[tid] = 0.f;
    int row0 = blockIdx.x * 64;
    if (tid < 64) {
        sBatch[tid] = (row0 + tid < N_NODES) ? batch[row0 + tid] : -1;
        sDeg[tid] = 0;
    }

    // ---- tile init: RAW own rows (affine deferred to fragment assembly)
#pragma unroll
    for (int r = 0; r < 16; r++) {
        int row = wave * 16 + r, grow = row0 + row;
        tile[row * TS + lane] = (grow < N_NODES) ? h[(size_t)grow * DIM + lane] : 0.f;
    }
    __syncthreads();

    // ---- edge gather: native ds_add_f32, unroll 8 for MLP depth
    int estart = boff[blockIdx.x * NSUB];
    int eend   = boff[blockIdx.x * NSUB + NSUB];
    int total  = eend - estart;
    int chunk  = (total + 3) >> 2;
    int a0 = estart + wave * chunk;
    int a1 = a0 + chunk; if (a1 > eend) a1 = eend;
    int i = a0;
    for (; i + 8 <= a1; i += 8) {
        unsigned e0 = ebuf[i],     e1 = ebuf[i + 1], e2 = ebuf[i + 2], e3 = ebuf[i + 3];
        unsigned e4 = ebuf[i + 4], e5 = ebuf[i + 5], e6 = ebuf[i + 6], e7 = ebuf[i + 7];
        unsigned eL = (lane < 8) ? ebuf[i + lane] : 0u;
        float v0 = h[(size_t)(e0 >> 6) * DIM + lane];
        float v1 = h[(size_t)(e1 >> 6) * DIM + lane];
        float v2 = h[(size_t)(e2 >> 6) * DIM + lane];
        float v3 = h[(size_t)(e3 >> 6) * DIM + lane];
        float v4 = h[(size_t)(e4 >> 6) * DIM + lane];
        float v5 = h[(size_t)(e5 >> 6) * DIM + lane];
        float v6 = h[(size_t)(e6 >> 6) * DIM + lane];
        float v7 = h[(size_t)(e7 >> 6) * DIM + lane];
        lds_fadd(&tile[(e0 & 63) * TS + lane], v0);
        lds_fadd(&tile[(e1 & 63) * TS + lane], v1);
        lds_fadd(&tile[(e2 & 63) * TS + lane], v2);
        lds_fadd(&tile[(e3 & 63) * TS + lane], v3);
        lds_fadd(&tile[(e4 & 63) * TS + lane], v4);
        lds_fadd(&tile[(e5 & 63) * TS + lane], v5);
        lds_fadd(&tile[(e6 & 63) * TS + lane], v6);
        lds_fadd(&tile[(e7 & 63) * TS + lane], v7);
        if (lane < 8) atomicAdd(&sDeg[eL & 63], 1);   // native ds_add_u32
    }
    for (; i < a1; i++) {
        unsigned e = ebuf[i];
        float v = h[(size_t)(e >> 6) * DIM + lane];
        lds_fadd(&tile[(e & 63) * TS + lane], v);
        if (lane == 0) atomicAdd(&sDeg[e & 63], 1);
    }
    __syncthreads();

    // ---- A fragments: input = sc (.) tile + (1+deg)*sh
    int m = lane & 15, quad = lane >> 4;
    float degf = 1.f + (float)sDeg[wave * 16 + m];
    float4 sc0, sc1, sc2, sc3, sh0, sh1, sh2, sh3;
    if (ss) {
        sc0 = *(const float4*)&ss[quad * 8];
        sc1 = *(const float4*)&ss[quad * 8 + 4];
        sc2 = *(const float4*)&ss[32 + quad * 8];
        sc3 = *(const float4*)&ss[32 + quad * 8 + 4];
        sh0 = *(const float4*)&ss[DIM + quad * 8];
        sh1 = *(const float4*)&ss[DIM + quad * 8 + 4];
        sh2 = *(const float4*)&ss[DIM + 32 + quad * 8];
        sh3 = *(const float4*)&ss[DIM + 32 + quad * 8 + 4];
    } else {
        sc0 = sc1 = sc2 = sc3 = (float4){1.f, 1.f, 1.f, 1.f};
        sh0 = sh1 = sh2 = sh3 = (float4){0.f, 0.f, 0.f, 0.f};
    }
    const float* tw = &tile[(wave * 16 + m) * TS];
    float4 a0f = affine4(*(const float4*)&tw[quad * 8],          sc0, degf, sh0);
    float4 a1f = affine4(*(const float4*)&tw[quad * 8 + 4],      sc1, degf, sh1);
    float4 a2f = affine4(*(const float4*)&tw[32 + quad * 8],     sc2, degf, sh2);
    float4 a3f = affine4(*(const float4*)&tw[32 + quad * 8 + 4], sc3, degf, sh3);
    short8 Ah0, Al0, Ah1, Al1;
    split8(a0f, a1f, &Ah0, &Al0);
    split8(a2f, a3f, &Ah1, &Al1);

    // ---- GEMM1 (split-bf16: AhBh + AhBl + AlBh)
    floatx4 acc[4];
#pragma unroll
    for (int nt = 0; nt < 4; nt++) acc[nt] = (floatx4){0.f, 0.f, 0.f, 0.f};
#pragma unroll
    for (int nt = 0; nt < 4; nt++) {
#pragma unroll
        for (int ks = 0; ks < 2; ks++) {
            const short8 Bh = *(const short8*)(wfL + (nt * 2 + ks) * 512 + lane * 8);
            const short8 Bl = *(const short8*)(wfL + 4096 + (nt * 2 + ks) * 512 + lane * 8);
            short8 Ahf = ks ? Ah1 : Ah0;
            short8 Alf = ks ? Al1 : Al0;
            acc[nt] = __builtin_amdgcn_mfma_f32_16x16x32_bf16(Ahf, Bh, acc[nt], 0, 0, 0);
            acc[nt] = __builtin_amdgcn_mfma_f32_16x16x32_bf16(Ahf, Bl, acc[nt], 0, 0, 0);
            acc[nt] = __builtin_amdgcn_mfma_f32_16x16x32_bf16(Alf, Bh, acc[nt], 0, 0, 0);
        }
    }

    // ---- bias+relu, park hidden in wave-private LDS, reload as A-fragments
    float* Hs = sH[wave];
#pragma unroll
    for (int nt = 0; nt < 4; nt++) {
        int col = nt * 16 + m;
        float b = B1[col];
#pragma unroll
        for (int r = 0; r < 4; r++) {
            int lr = quad * 4 + r;
            Hs[lr * TS + col] = fmaxf(acc[nt][r] + b, 0.f);
        }
    }
    float4 h0 = *(const float4*)&Hs[m * TS + quad * 8];
    float4 h1 = *(const float4*)&Hs[m * TS + quad * 8 + 4];
    float4 h2 = *(const float4*)&Hs[m * TS + 32 + quad * 8];
    float4 h3 = *(const float4*)&Hs[m * TS + 32 + quad * 8 + 4];
    short8 Hh0, Hl0, Hh1, Hl1;
    split8(h0, h1, &Hh0, &Hl0);
    split8(h2, h3, &Hh1, &Hl1);

    // ---- GEMM2
    floatx4 acc2[4];
#pragma unroll
    for (int nt = 0; nt < 4; nt++) acc2[nt] = (floatx4){0.f, 0.f, 0.f, 0.f};
    const unsigned short* wg2 = wfL + 8192;
#pragma unroll
    for (int nt = 0; nt < 4; nt++) {
#pragma unroll
        for (int ks = 0; ks < 2; ks++) {
            const short8 Bh = *(const short8*)(wg2 + (nt * 2 + ks) * 512 + lane * 8);
            const short8 Bl = *(const short8*)(wg2 + 4096 + (nt * 2 + ks) * 512 + lane * 8);
            short8 Ahf = ks ? Hh1 : Hh0;
            short8 Alf = ks ? Hl1 : Hl0;
            acc2[nt] = __builtin_amdgcn_mfma_f32_16x16x32_bf16(Ahf, Bh, acc2[nt], 0, 0, 0);
            acc2[nt] = __builtin_amdgcn_mfma_f32_16x16x32_bf16(Ahf, Bl, acc2[nt], 0, 0, 0);
            acc2[nt] = __builtin_amdgcn_mfma_f32_16x16x32_bf16(Alf, Bh, acc2[nt], 0, 0, 0);
        }
    }

    // ---- epilogue: raw z write + BN partials + per-graph raw pooling
    int gfirst = sBatch[wave * 16], glast = sBatch[wave * 16 + 15];
    bool uni = (gfirst == glast) && (gfirst >= 0);
#pragma unroll
    for (int nt = 0; nt < 4; nt++) {
        int col = nt * 16 + m;
        float b = B2[col];
        float vv[4];
        float s = 0.f, s2 = 0.f;
#pragma unroll
        for (int r = 0; r < 4; r++) {
            int gr = row0 + wave * 16 + quad * 4 + r;
            float v = fmaxf(acc2[nt][r] + b, 0.f);
            if (gr < N_NODES) {
                if (write_z) z_out[(size_t)gr * DIM + col] = v;
                s += v;
                s2 = fmaf(v, v, s2);
                vv[r] = v;
            } else {
                vv[r] = 0.f;
            }
        }
        float sf = s, s2f = s2;
        sf  += __shfl_xor(sf, 16);  sf  += __shfl_xor(sf, 32);
        s2f += __shfl_xor(s2f, 16); s2f += __shfl_xor(s2f, 32);
        if (quad == 0) {
            lds_fadd(&sSum[col], sf);
            lds_fadd(&sSum[DIM + col], s2f);
            if (uni) atomicAdd(&praw[(size_t)gfirst * DIM + col], sf);
        }
        if (!uni) {
            int cur = -1; float run = 0.f;
#pragma unroll
            for (int r = 0; r < 4; r++) {
                int g = sBatch[wave * 16 + quad * 4 + r];
                if (g != cur) {
                    if (cur >= 0 && run != 0.f)
                        atomicAdd(&praw[(size_t)cur * DIM + col], run);
                    run = 0.f; cur = g;
                }
                run += vv[r];
            }
            if (cur >= 0 && run != 0.f)
                atomicAdd(&praw[(size_t)cur * DIM + col], run);
        }
    }
    __syncthreads();
    if (tid < 2 * DIM)
        atomicAdd(&sums_part[(size_t)(blockIdx.x & (N_PART - 1)) * 2 * DIM + tid], sSum[tid]);
}

// --------------------------------------------- BN scale/shift from partials
__global__ void finalize_stats(const float* __restrict__ sp,
                               const float* __restrict__ gamma,
                               const float* __restrict__ beta,
                               float* __restrict__ ss) {
    int c = threadIdx.x;
    float s = 0.f, q = 0.f;
    for (int p = 0; p < N_PART; p++) {
        s += sp[p * 2 * DIM + c];
        q += sp[p * 2 * DIM + DIM + c];
    }
    const float inv_n = 1.0f / (float)N_NODES;
    float mu  = s * inv_n;
    float var = q * inv_n - mu * mu;
    float scale = gamma[c] / sqrtf(var + BN_EPS);
    ss[c]       = scale;
    ss[DIM + c] = beta[c] - mu * scale;
}

// ------------------- pooled[g][L*64+c] = sc*praw + cnt_g*sh
__global__ __launch_bounds__(256) void assemble_pooled(const float* __restrict__ praw,
                                                       const float* __restrict__ ssAll,
                                                       const int* __restrict__ cntg,
                                                       float* __restrict__ pooled) {
    int idx = blockIdx.x * 256 + threadIdx.x;
    if (idx >= N_GRAPHS * D3) return;
    int g = idx / D3, j = idx - g * D3, L = j >> 6, c = j & 63;
    float sc = ssAll[L * 2 * DIM + c], sh = ssAll[L * 2 * DIM + DIM + c];
    pooled[idx] = fmaf(sc, praw[((size_t)L * N_GRAPHS + g) * DIM + c],
                       (float)cntg[g] * sh);
}

// ------------------------------------------------ final 2-layer MLP on pooled
__global__ __launch_bounds__(192) void final_mlp(const float* __restrict__ pooled,
    const float* __restrict__ PW1, const float* __restrict__ PB1,
    const float* __restrict__ PW2, const float* __restrict__ PB2,
    float* __restrict__ out) {
    __shared__ float row[D3];
    __shared__ float hid[D3];
    int g = blockIdx.x, j = threadIdx.x;
    row[j] = pooled[(size_t)g * D3 + j];
    __syncthreads();
    float acc = PB1[j];
    for (int k = 0; k < D3; k++) acc = fmaf(row[k], PW1[k * D3 + j], acc);
    hid[j] = fmaxf(acc, 0.f);
    __syncthreads();
    float acc2 = PB2[j];
    for (int k = 0; k < D3; k++) acc2 = fmaf(hid[k], PW2[k * D3 + j], acc2);
    out[(size_t)g * D3 + j] = acc2;
}

extern "C" void kernel_launch(void* const* d_in, const int* in_sizes, int n_in,
                              void* d_out, int out_size, void* d_ws, size_t ws_size,
                              hipStream_t stream) {
    const float* x     = (const float*)d_in[0];
    const int*   ei    = (const int*)d_in[1];
    const int*   batch = (const int*)d_in[2];
    const float* W1    = (const float*)d_in[3];
    const float* B1    = (const float*)d_in[4];
    const float* W2    = (const float*)d_in[5];
    const float* B2    = (const float*)d_in[6];
    const float* gamma = (const float*)d_in[7];
    const float* beta  = (const float*)d_in[8];
    const float* PW1   = (const float*)d_in[9];
    const float* PB1   = (const float*)d_in[10];
    const float* PW2   = (const float*)d_in[11];
    const float* PB2   = (const float*)d_in[12];
    float* out = (float*)d_out;

    // -------- workspace layout
    float*    bufA   = (float*)d_ws;                               // 3,200,000
    float*    bufB   = bufA + (size_t)N_NODES * DIM;               // 3,200,000
    unsigned* ebuf   = (unsigned*)(bufB + (size_t)N_NODES * DIM);  // 800,000
    int*      boff   = (int*)(ebuf + N_EDGES);                     // 6,260
    unsigned short* wfrag = (unsigned short*)(boff + 6260);        // 49,152 u16
    float*    ssbuf  = (float*)(wfrag + 49152);                    // 384
    float*    pooled = ssbuf + N_LAYERS * 2 * DIM;                 // 49,152
    // ---- zeroed region starts here
    int*      bcnt   = (int*)(pooled + N_GRAPHS * D3);             // 6,256
    int*      bfill  = bcnt + NCTR;                                // 6,256
    int*      cntg   = bfill + NCTR;                               // 256
    float*    sums_part = (float*)(cntg + N_GRAPHS);               // 3*64*128
    float*    praw   = sums_part + N_LAYERS * N_PART * 2 * DIM;    // 3*256*64

    const int* src = ei;
    const int* dst = ei + N_EDGES;

    const size_t zero_bytes =
        (size_t)(2 * NCTR + N_GRAPHS) * sizeof(int) +
        (size_t)(N_LAYERS * N_PART * 2 * DIM + N_LAYERS * N_GRAPHS * DIM) * sizeof(float);
    hipMemsetAsync(bcnt, 0, zero_bytes, stream);

    // -------- edge partition + weight prep + graph counts
    const int PB = (N_EDGES + 4095) / 4096;
    pass1_hist<<<PB, 256, 0, stream>>>(dst, bcnt);
    scan_all<<<1, 1024, 0, stream>>>(bcnt, boff);
    pass2_part<<<PB, 256, 0, stream>>>(src, dst, boff, bfill, ebuf);
    prep_weights<<<(N_LAYERS * 2 * 4096 + 255) / 256, 256, 0, stream>>>(W1, W2, wfrag);
    count_graphs<<<(N_NODES / 8 + 255) / 256, 256, 0, stream>>>(batch, cntg);

    // -------- fused layers
    const float* P = x;
    float* Q = bufA;
    const float* ssPrev = nullptr;
    for (int L = 0; L < N_LAYERS; ++L) {
        int write_z = (L < N_LAYERS - 1);
        gin_layer<<<NBKT, 256, 0, stream>>>(
            P, ssPrev, ebuf, boff,
            wfrag + (size_t)L * 2 * 8192,
            B1 + (size_t)L * DIM, B2 + (size_t)L * DIM,
            Q, write_z,
            sums_part + (size_t)L * N_PART * 2 * DIM,
            praw + (size_t)L * N_GRAPHS * DIM,
            batch);
        finalize_stats<<<1, DIM, 0, stream>>>(sums_part + (size_t)L * N_PART * 2 * DIM,
                                              gamma + (size_t)L * DIM,
                                              beta + (size_t)L * DIM,
                                              ssbuf + (size_t)L * 2 * DIM);
        ssPrev = ssbuf + (size_t)L * 2 * DIM;
        P = Q;
        Q = (Q == bufA) ? bufB : bufA;
    }

    assemble_pooled<<<(N_GRAPHS * D3 + 255) / 256, 256, 0, stream>>>(praw, ssbuf, cntg, pooled);
    final_mlp<<<N_GRAPHS, 192, 0, stream>>>(pooled, PW1, PB1, PW2, PB2, out);
}

// Round 6
// 350.179 us; speedup vs baseline: 3.5529x; 3.5444x over previous
//
#include <hip/hip_runtime.h>

#define N_NODES 50000
#define N_EDGES 800000
#define DIM 64
#define N_LAYERS 3
#define N_GRAPHS 256
#define BN_EPS 1e-5f
#define TM 8
#define D3 (DIM * N_LAYERS)
#define N_PART 64
#define NBKT 782          // ceil(50000/64) destination buckets
#define NSUB 8
#define NCTR (NBKT * NSUB)
#define CAP 2048          // LDS staging capacity per bucket (mean 1023, sigma 32)

typedef __attribute__((ext_vector_type(8))) short short8;
typedef __attribute__((ext_vector_type(4))) float floatx4;

// ---------------------------------------------------------- bf16 split utils
__device__ inline unsigned short bf16_rn(float f) {
    unsigned u = __float_as_uint(f);
    u += 0x7FFF + ((u >> 16) & 1);
    return (unsigned short)(u >> 16);
}
__device__ inline float bf16_f(unsigned short b) {
    return __uint_as_float(((unsigned)b) << 16);
}
__device__ inline void split8(float4 a, float4 b, short8* hi, short8* lo) {
    float v[8] = {a.x, a.y, a.z, a.w, b.x, b.y, b.z, b.w};
#pragma unroll
    for (int i = 0; i < 8; i++) {
        unsigned short h = bf16_rn(v[i]);
        (*hi)[i] = (short)h;
        (*lo)[i] = (short)bf16_rn(v[i] - bf16_f(h));
    }
}

// ---------------------------------------------- pass 1: per-(bucket,sub) hist
__global__ __launch_bounds__(256) void pass1_hist(const int* __restrict__ dst,
                                                  int* __restrict__ bcnt) {
    __shared__ int hcnt[NBKT];
    for (int i = threadIdx.x; i < NBKT; i += 256) hcnt[i] = 0;
    __syncthreads();
    int sub = blockIdx.x & (NSUB - 1);
    int base = blockIdx.x * 4096;
#pragma unroll
    for (int k = 0; k < 16; k++) {
        int e = base + k * 256 + threadIdx.x;
        if (e < N_EDGES) atomicAdd(&hcnt[dst[e] >> 6], 1);
    }
    __syncthreads();
    for (int i = threadIdx.x; i < NBKT; i += 256) {
        int c = hcnt[i];
        if (c) atomicAdd(&bcnt[i * NSUB + sub], c);
    }
}

// -------------------------------------- exclusive scan of 6256 counters
__global__ __launch_bounds__(1024) void scan_all(const int* __restrict__ bcnt,
                                                 int* __restrict__ boff) {
    __shared__ int tsum[1024];
    int t = threadIdx.x;
    const int C = (NCTR + 1023) / 1024;   // 7
    int base = t * C;
    int loc[7];
    int s = 0;
    for (int i = 0; i < C; i++) {
        int idx = base + i;
        int v = (idx < NCTR) ? bcnt[idx] : 0;
        loc[i] = s;
        s += v;
    }
    tsum[t] = s;
    __syncthreads();
    for (int off = 1; off < 1024; off <<= 1) {
        int v = (t >= off) ? tsum[t - off] : 0;
        __syncthreads();
        tsum[t] += v;
        __syncthreads();
    }
    int excl = (t > 0) ? tsum[t - 1] : 0;
    for (int i = 0; i < C; i++) {
        int idx = base + i;
        if (idx < NCTR) boff[idx] = excl + loc[i];
    }
    if (t == 0) boff[NCTR] = N_EDGES;
}

// ------------------------- pass 2: partition edges, pack src<<6 | (dst&63)
__global__ __launch_bounds__(256) void pass2_part(const int* __restrict__ src,
                                                  const int* __restrict__ dst,
                                                  const int* __restrict__ boff,
                                                  int* __restrict__ bfill,
                                                  unsigned* __restrict__ ebuf) {
    int sub = blockIdx.x & (NSUB - 1);
    int base = blockIdx.x * 4096;
#pragma unroll
    for (int k = 0; k < 16; k++) {
        int e = base + k * 256 + threadIdx.x;
        if (e < N_EDGES) {
            int d = dst[e];
            int b = d >> 6;
            int pos = boff[b * NSUB + sub] + atomicAdd(&bfill[b * NSUB + sub], 1);
            ebuf[pos] = ((unsigned)src[e] << 6) | (unsigned)(d & 63);
        }
    }
}

// --------- counting-sort each bucket's edges by dst&63 -> per-node CSR + rp
// one block per bucket; writes land in the bucket's dense 4KB csr region
__global__ __launch_bounds__(256) void bucket_sort(const unsigned* __restrict__ ebuf,
                                                   const int* __restrict__ boff,
                                                   int* __restrict__ csr,
                                                   int* __restrict__ rp) {
    __shared__ unsigned ent[CAP];
    __shared__ int cnt[64], basea[64], fill[64];
    int b = blockIdx.x, tid = threadIdx.x;
    int start = boff[b * NSUB], end = boff[b * NSUB + NSUB];
    int T = end - start;
    if (tid < 64) cnt[tid] = 0;
    bool use_lds = (T <= CAP);          // block-uniform
    if (use_lds)
        for (int i = tid; i < T; i += 256) ent[i] = ebuf[start + i];
    __syncthreads();
    for (int i = tid; i < T; i += 256) {
        unsigned e = use_lds ? ent[i] : ebuf[start + i];
        atomicAdd(&cnt[e & 63], 1);
    }
    __syncthreads();
    if (tid < 64) {                      // wave-0 exclusive scan of 64 counts
        int v = cnt[tid], x = v;
#pragma unroll
        for (int off = 1; off < 64; off <<= 1) {
            int y = __shfl_up(x, off);
            if (tid >= off) x += y;
        }
        basea[tid] = x - v;
        fill[tid] = 0;
        rp[b * 64 + tid] = start + x - v;   // absolute row ptr (monotone)
    }
    __syncthreads();
    for (int i = tid; i < T; i += 256) {
        unsigned e = use_lds ? ent[i] : ebuf[start + i];
        int c = e & 63;
        int pos = basea[c] + atomicAdd(&fill[c], 1);
        csr[start + pos] = (int)(e >> 6);
    }
}

// ------------------------------- gather: z[i] = h[i] + sum_{j->i} h[j]
__global__ __launch_bounds__(256) void gather_kernel(const float* __restrict__ h,
                                                     float* __restrict__ z,
                                                     const int* __restrict__ rp,
                                                     const int* __restrict__ csr) {
    int node = blockIdx.x * 4 + (threadIdx.x >> 6);
    if (node >= N_NODES) return;
    int lane = threadIdx.x & 63;
    float acc = h[(size_t)node * DIM + lane];
    int e = rp[node], end = rp[node + 1];
    for (; e + 8 <= end; e += 8) {
        int s0 = csr[e],     s1 = csr[e + 1], s2 = csr[e + 2], s3 = csr[e + 3];
        int s4 = csr[e + 4], s5 = csr[e + 5], s6 = csr[e + 6], s7 = csr[e + 7];
        float v0 = h[(size_t)s0 * DIM + lane];
        float v1 = h[(size_t)s1 * DIM + lane];
        float v2 = h[(size_t)s2 * DIM + lane];
        float v3 = h[(size_t)s3 * DIM + lane];
        float v4 = h[(size_t)s4 * DIM + lane];
        float v5 = h[(size_t)s5 * DIM + lane];
        float v6 = h[(size_t)s6 * DIM + lane];
        float v7 = h[(size_t)s7 * DIM + lane];
        acc += ((v0 + v1) + (v2 + v3)) + ((v4 + v5) + (v6 + v7));
    }
    for (; e < end; e++) acc += h[(size_t)csr[e] * DIM + lane];
    z[(size_t)node * DIM + lane] = acc;
}

// --------------- pack W1/W2 into MFMA B-operand fragments, split bf16 hi/lo
__global__ __launch_bounds__(256) void prep_weights(const float* __restrict__ W1,
                                                    const float* __restrict__ W2,
                                                    unsigned short* __restrict__ wf) {
    int idx = blockIdx.x * 256 + threadIdx.x;
    if (idx >= N_LAYERS * 2 * 4096) return;
    int j    = idx & 7;
    int lane = (idx >> 3) & 63;
    int ks   = (idx >> 9) & 1;
    int nt   = (idx >> 10) & 3;
    int gemm = (idx >> 12) & 1;
    int layer = idx >> 13;
    int n = nt * 16 + (lane & 15);
    int k = ks * 32 + (lane >> 4) * 8 + j;
    const float* W = (gemm ? W2 : W1) + (size_t)layer * DIM * DIM;
    float w = W[k * DIM + n];
    unsigned short hi = bf16_rn(w);
    unsigned short lo = bf16_rn(w - bf16_f(hi));
    size_t base = ((size_t)layer * 2 + gemm) * 8192;
    int f = nt * 2 + ks;
    wf[base + f * 512 + lane * 8 + j]        = hi;
    wf[base + 4096 + f * 512 + lane * 8 + j] = lo;
}

// ---------------- MFMA MLP: z = relu(relu(zW1+B1)W2+B2), + BN stat partials
#define HS_STRIDE 68
__global__ __launch_bounds__(256) void mlp_mfma(float* __restrict__ z,
    const unsigned short* __restrict__ wfL,
    const float* __restrict__ B1, const float* __restrict__ B2,
    float* __restrict__ sums_part) {
    __shared__ float sH[4][16 * HS_STRIDE];
    __shared__ float sSum[2 * DIM];

    int tid = threadIdx.x, wave = tid >> 6, lane = tid & 63;
    if (tid < 2 * DIM) sSum[tid] = 0.f;
    __syncthreads();

    int m = lane & 15, quad = lane >> 4;
    int row0 = blockIdx.x * 64 + wave * 16;
    int grow = row0 + m;
    int ar = grow < N_NODES ? grow : N_NODES - 1;

    const float4* zr = (const float4*)(z + (size_t)ar * DIM);
    float4 a0 = zr[quad * 2],     a1 = zr[quad * 2 + 1];
    float4 a2 = zr[8 + quad * 2], a3 = zr[8 + quad * 2 + 1];
    short8 Ah0, Al0, Ah1, Al1;
    split8(a0, a1, &Ah0, &Al0);
    split8(a2, a3, &Ah1, &Al1);

    floatx4 acc[4];
#pragma unroll
    for (int nt = 0; nt < 4; nt++) acc[nt] = (floatx4){0.f, 0.f, 0.f, 0.f};
#pragma unroll
    for (int nt = 0; nt < 4; nt++) {
#pragma unroll
        for (int ks = 0; ks < 2; ks++) {
            const short8 Bh = *(const short8*)(wfL + (nt * 2 + ks) * 512 + lane * 8);
            const short8 Bl = *(const short8*)(wfL + 4096 + (nt * 2 + ks) * 512 + lane * 8);
            short8 Ahf = ks ? Ah1 : Ah0;
            short8 Alf = ks ? Al1 : Al0;
            acc[nt] = __builtin_amdgcn_mfma_f32_16x16x32_bf16(Ahf, Bh, acc[nt], 0, 0, 0);
            acc[nt] = __builtin_amdgcn_mfma_f32_16x16x32_bf16(Ahf, Bl, acc[nt], 0, 0, 0);
            acc[nt] = __builtin_amdgcn_mfma_f32_16x16x32_bf16(Alf, Bh, acc[nt], 0, 0, 0);
        }
    }

    float* Hs = sH[wave];
#pragma unroll
    for (int nt = 0; nt < 4; nt++) {
        int col = nt * 16 + m;
        float b = B1[col];
#pragma unroll
        for (int r = 0; r < 4; r++) {
            int lr = quad * 4 + r;
            Hs[lr * HS_STRIDE + col] = fmaxf(acc[nt][r] + b, 0.f);
        }
    }
    float4 h0 = *(const float4*)&Hs[m * HS_STRIDE + quad * 8];
    float4 h1 = *(const float4*)&Hs[m * HS_STRIDE + quad * 8 + 4];
    float4 h2 = *(const float4*)&Hs[m * HS_STRIDE + 32 + quad * 8];
    float4 h3 = *(const float4*)&Hs[m * HS_STRIDE + 32 + quad * 8 + 4];
    short8 Hh0, Hl0, Hh1, Hl1;
    split8(h0, h1, &Hh0, &Hl0);
    split8(h2, h3, &Hh1, &Hl1);

    floatx4 acc2[4];
#pragma unroll
    for (int nt = 0; nt < 4; nt++) acc2[nt] = (floatx4){0.f, 0.f, 0.f, 0.f};
    const unsigned short* wg2 = wfL + 8192;
#pragma unroll
    for (int nt = 0; nt < 4; nt++) {
#pragma unroll
        for (int ks = 0; ks < 2; ks++) {
            const short8 Bh = *(const short8*)(wg2 + (nt * 2 + ks) * 512 + lane * 8);
            const short8 Bl = *(const short8*)(wg2 + 4096 + (nt * 2 + ks) * 512 + lane * 8);
            short8 Ahf = ks ? Hh1 : Hh0;
            short8 Alf = ks ? Hl1 : Hl0;
            acc2[nt] = __builtin_amdgcn_mfma_f32_16x16x32_bf16(Ahf, Bh, acc2[nt], 0, 0, 0);
            acc2[nt] = __builtin_amdgcn_mfma_f32_16x16x32_bf16(Ahf, Bl, acc2[nt], 0, 0, 0);
            acc2[nt] = __builtin_amdgcn_mfma_f32_16x16x32_bf16(Alf, Bh, acc2[nt], 0, 0, 0);
        }
    }

#pragma unroll
    for (int nt = 0; nt < 4; nt++) {
        int col = nt * 16 + m;
        float b = B2[col];
        float s = 0.f, s2 = 0.f;
#pragma unroll
        for (int r = 0; r < 4; r++) {
            int gr = row0 + quad * 4 + r;
            float v = fmaxf(acc2[nt][r] + b, 0.f);
            if (gr < N_NODES) {
                z[(size_t)gr * DIM + col] = v;
                s += v;
                s2 = fmaf(v, v, s2);
            }
        }
        s  += __shfl_xor(s, 16);  s  += __shfl_xor(s, 32);
        s2 += __shfl_xor(s2, 16); s2 += __shfl_xor(s2, 32);
        if (quad == 0) {
            atomicAdd(&sSum[col], s);
            atomicAdd(&sSum[DIM + col], s2);
        }
    }
    __syncthreads();
    if (tid < 2 * DIM)
        atomicAdd(&sums_part[(size_t)(blockIdx.x & (N_PART - 1)) * 2 * DIM + tid], sSum[tid]);
}

// --------------------------------------------- BN scale/shift from partials
__global__ void finalize_stats(const float* __restrict__ sp,
                               const float* __restrict__ gamma,
                               const float* __restrict__ beta,
                               float* __restrict__ ss) {
    int c = threadIdx.x;
    float s = 0.f, q = 0.f;
    for (int p = 0; p < N_PART; p++) {
        s += sp[p * 2 * DIM + c];
        q += sp[p * 2 * DIM + DIM + c];
    }
    const float inv_n = 1.0f / (float)N_NODES;
    float mu  = s * inv_n;
    float var = q * inv_n - mu * mu;
    float sc  = gamma[c] / sqrtf(var + BN_EPS);
    ss[c]       = sc;
    ss[DIM + c] = beta[c] - mu * sc;
}

// ----------------------------- BN apply (in place) + global_add_pool
__global__ __launch_bounds__(256) void bn_pool_kernel(float* __restrict__ z,
    const float* __restrict__ ss, const int* __restrict__ batch,
    float* __restrict__ pooled, int layer) {
    int grp = blockIdx.x * 4 + (threadIdx.x >> 6);
    if (grp >= N_NODES / 8) return;
    int c = threadIdx.x & 63;
    int n0 = grp * 8;
    float sc = ss[c], sh = ss[DIM + c];
    float run = 0.f;
    int cur = batch[n0];
#pragma unroll
    for (int r = 0; r < 8; r++) {
        int n = n0 + r;
        float v = fmaf(z[(size_t)n * DIM + c], sc, sh);
        z[(size_t)n * DIM + c] = v;
        int b = batch[n];
        if (b != cur) {
            atomicAdd(&pooled[(size_t)cur * D3 + layer * DIM + c], run);
            run = 0.f;
            cur = b;
        }
        run += v;
    }
    atomicAdd(&pooled[(size_t)cur * D3 + layer * DIM + c], run);
}

// ------------------------------------------------ final 2-layer MLP on pooled
__global__ __launch_bounds__(192) void final_mlp(const float* __restrict__ pooled,
    const float* __restrict__ PW1, const float* __restrict__ PB1,
    const float* __restrict__ PW2, const float* __restrict__ PB2,
    float* __restrict__ out) {
    __shared__ float row[D3];
    __shared__ float hid[D3];
    int g = blockIdx.x, j = threadIdx.x;
    row[j] = pooled[(size_t)g * D3 + j];
    __syncthreads();
    float acc = PB1[j];
    for (int k = 0; k < D3; k++) acc = fmaf(row[k], PW1[k * D3 + j], acc);
    hid[j] = fmaxf(acc, 0.f);
    __syncthreads();
    float acc2 = PB2[j];
    for (int k = 0; k < D3; k++) acc2 = fmaf(hid[k], PW2[k * D3 + j], acc2);
    out[(size_t)g * D3 + j] = acc2;
}

extern "C" void kernel_launch(void* const* d_in, const int* in_sizes, int n_in,
                              void* d_out, int out_size, void* d_ws, size_t ws_size,
                              hipStream_t stream) {
    const float* x     = (const float*)d_in[0];
    const int*   ei    = (const int*)d_in[1];
    const int*   batch = (const int*)d_in[2];
    const float* W1    = (const float*)d_in[3];
    const float* B1    = (const float*)d_in[4];
    const float* W2    = (const float*)d_in[5];
    const float* B2    = (const float*)d_in[6];
    const float* gamma = (const float*)d_in[7];
    const float* beta  = (const float*)d_in[8];
    const float* PW1   = (const float*)d_in[9];
    const float* PB1   = (const float*)d_in[10];
    const float* PW2   = (const float*)d_in[11];
    const float* PB2   = (const float*)d_in[12];
    float* out = (float*)d_out;

    // -------- workspace layout (ebuf aliases bufB: dead before layer 1)
    float*    bufA  = (float*)d_ws;                              // 3,200,000 f
    float*    bufB  = bufA + (size_t)N_NODES * DIM;              // 3,200,000 f
    unsigned* ebuf  = (unsigned*)bufB;                           // 800,000 u32 (alias)
    int*      csr   = (int*)(bufB + (size_t)N_NODES * DIM);      // 800,000 i
    int*      rp    = csr + N_EDGES;                             // 50,056 i (782*64 pad)
    int*      boff  = rp + 50056;                                // 6,264 i
    unsigned short* wfrag = (unsigned short*)(boff + 6264);      // 49,152 u16
    float*    ssbuf = (float*)(wfrag + 49152);                   // 384 f
    // ---- zeroed region
    int*      bcnt  = (int*)(ssbuf + N_LAYERS * 2 * DIM);        // 6,256 i
    int*      bfill = bcnt + NCTR;                               // 6,256 i
    float*    pooled = (float*)(bfill + NCTR);                   // 49,152 f
    float*    sums_part = pooled + N_GRAPHS * D3;                // 24,576 f

    const int* src = ei;
    const int* dst = ei + N_EDGES;

    const size_t zero_bytes =
        (size_t)(2 * NCTR) * sizeof(int) +
        (size_t)(N_GRAPHS * D3 + N_LAYERS * N_PART * 2 * DIM) * sizeof(float);
    hipMemsetAsync(bcnt, 0, zero_bytes, stream);

    // -------- CSR build: bucket partition + per-bucket counting sort
    const int PB = (N_EDGES + 4095) / 4096;       // 196
    pass1_hist<<<PB, 256, 0, stream>>>(dst, bcnt);
    scan_all<<<1, 1024, 0, stream>>>(bcnt, boff);
    pass2_part<<<PB, 256, 0, stream>>>(src, dst, boff, bfill, ebuf);
    bucket_sort<<<NBKT, 256, 0, stream>>>(ebuf, boff, csr, rp);
    prep_weights<<<(N_LAYERS * 2 * 4096 + 255) / 256, 256, 0, stream>>>(W1, W2, wfrag);

    // -------- layers (round-3 proven pipeline)
    const float* P = x;
    float* Q = bufA;
    const int MB = (N_NODES + 63) / 64;   // 782
    for (int L = 0; L < N_LAYERS; ++L) {
        gather_kernel<<<(N_NODES + 3) / 4, 256, 0, stream>>>(P, Q, rp, csr);
        mlp_mfma<<<MB, 256, 0, stream>>>(
            Q, wfrag + (size_t)L * 2 * 8192, B1 + (size_t)L * DIM, B2 + (size_t)L * DIM,
            sums_part + (size_t)L * N_PART * 2 * DIM);
        finalize_stats<<<1, DIM, 0, stream>>>(sums_part + (size_t)L * N_PART * 2 * DIM,
                                              gamma + (size_t)L * DIM,
                                              beta + (size_t)L * DIM,
                                              ssbuf + (size_t)L * 2 * DIM);
        bn_pool_kernel<<<(N_NODES / 8 + 3) / 4, 256, 0, stream>>>(
            Q, ssbuf + (size_t)L * 2 * DIM, batch, pooled, L);
        P = Q;
        Q = (Q == bufA) ? bufB : bufA;
    }
    final_mlp<<<N_GRAPHS, 192, 0, stream>>>(pooled, PW1, PB1, PW2, PB2, out);
}